// Round 7
// baseline (158.702 us; speedup 1.0000x reference)
//
#include <hip/hip_runtime.h>

#define TWO_PI 6.2831853071795864769f

typedef float floatx4 __attribute__((ext_vector_type(4)));
typedef float f32x16 __attribute__((ext_vector_type(16)));
typedef __bf16 bf16x8 __attribute__((ext_vector_type(8)));

__device__ __forceinline__ unsigned short f32_to_bf16(float f) {
    unsigned int u = __float_as_uint(f);
    u += 0x7fffu + ((u >> 16) & 1u);   // round-to-nearest-even
    return (unsigned short)(u >> 16);
}

__device__ __forceinline__ void gload_lds16(const void* g, void* l) {
    __builtin_amdgcn_global_load_lds(
        (__attribute__((address_space(1))) unsigned int*)g,
        (__attribute__((address_space(3))) unsigned int*)l, 16, 0, 0);
}

// ---------------------------------------------------------------------------
// Precompute per-(d,kq) coefficients (separate tiny kernel — L2-speed).
// coef row (32 floats): Ac[0..7]=2pi*E_w, u[0..7]=(2pi*std_p)^2*vsw, z[0..7],
//                       alpha, sqrt(2w/K), 2w/K
// ---------------------------------------------------------------------------
__global__ __launch_bounds__(256) void k_precompute(
    const float* __restrict__ z, const float* __restrict__ weight,
    const float* __restrict__ mu, const float* __restrict__ stdv,
    const float* __restrict__ alpha, const float* __restrict__ vmw,
    const float* __restrict__ vsw, float* __restrict__ coef)
{
    int kq = blockIdx.x * blockDim.x + threadIdx.x;
    if (kq >= 1024) return;
    int q = kq & 15;
    float w = weight[q];
    float t2k = w * (2.0f / 64.0f);
    float* c = coef + (size_t)kq * 32;
#pragma unroll
    for (int d = 0; d < 8; ++d) {
        float m = mu[d * 16 + q];
        float s = stdv[d * 16 + q];
        float mean_p = 1.0f / (m + 1e-8f);
        float std_p  = 1.0f / (TWO_PI * s + 1e-8f);
        float Ew  = mean_p + std_p * vmw[d * 1024 + kq];
        float sp2 = std_p * TWO_PI;
        c[d]      = TWO_PI * Ew;
        c[8 + d]  = sp2 * sp2 * vsw[d * 1024 + kq];
        c[16 + d] = z[d * 1024 + kq];
    }
    c[24] = alpha[kq];
    c[25] = sqrtf(t2k);
    c[26] = t2k;
}

// ---------------------------------------------------------------------------
// Elementwise kernel: 64 n-rows x 64 kq-cols per block, 256 threads.
// bf16 pairs packed to uint in main loop; ET transpose via uint LDS with
// conflict-free b128 ops. part[kq][NB] transposed partials (no atomics).
// ---------------------------------------------------------------------------
__global__ __launch_bounds__(256) void k_ephi(
    const float* __restrict__ X, const float* __restrict__ coef,
    float* __restrict__ Ephi, float* __restrict__ Ecos,
    unsigned short* __restrict__ ET, float* __restrict__ part,
    int N, int NB)
{
    __shared__ float Xs[64][8];
    __shared__ unsigned Ebu[64][36];   // [kq_local][n_pair]; pad 36 -> b128 ok
    __shared__ float red[256];

    const int tid = threadIdx.x;
    const int kq0 = blockIdx.x * 64;
    const int n0  = blockIdx.y * 64;

    for (int i = tid; i < 512; i += 256)
        Xs[i >> 3][i & 7] = X[(size_t)(n0 + (i >> 3)) * 8 + (i & 7)];
    __syncthreads();

    const int kql = tid & 63;
    const int kq  = kq0 + kql;
    const int nb  = (tid >> 6) * 16;

    const float* c = coef + (size_t)kq * 32;
    float Ac[8], u[8], zv[8];
    *(floatx4*)&Ac[0] = *(const floatx4*)(c + 0);
    *(floatx4*)&Ac[4] = *(const floatx4*)(c + 4);
    *(floatx4*)&u[0]  = *(const floatx4*)(c + 8);
    *(floatx4*)&u[4]  = *(const floatx4*)(c + 12);
    *(floatx4*)&zv[0] = *(const floatx4*)(c + 16);
    *(floatx4*)&zv[4] = *(const floatx4*)(c + 20);
    const float alp = c[24], sqw = c[25], t2k = c[26];

    float csum = 0.0f;
    unsigned pk[8];
    unsigned short prevb = 0;
#pragma unroll
    for (int nl = 0; nl < 16; ++nl) {
        const int n = nb + nl;
        floatx4 xa = *(const floatx4*)&Xs[n][0];
        floatx4 xb = *(const floatx4*)&Xs[n][4];
        float ph = 0.0f, s = 0.0f;
#pragma unroll
        for (int d = 0; d < 4; ++d) {
            float t = xa[d] - zv[d];
            ph = fmaf(Ac[d], t, ph);
            s  = fmaf(u[d], t * t, s);
        }
#pragma unroll
        for (int d = 0; d < 4; ++d) {
            float t = xb[d] - zv[4 + d];
            ph = fmaf(Ac[4 + d], t, ph);
            s  = fmaf(u[4 + d], t * t, s);
        }
        float cw  = __cosf(alp + ph);           // |arg| <~ few hundred: err ~1e-5
        float dec = __expf(-0.5f * s);
        float ep  = sqw * dec * cw;
        float d2  = dec * dec;
        float c2w = fmaf(2.0f * cw, cw, -1.0f); // cos(2(alpha+phase))
        float ec  = t2k * fmaf(0.5f * d2 * d2, c2w, 0.5f);
        csum += ec;
        size_t idx = (size_t)(n0 + n) * 1024 + kq;
        __builtin_nontemporal_store(ep, &Ephi[idx]);
        __builtin_nontemporal_store(ec, &Ecos[idx]);
        unsigned short b = f32_to_bf16(ep);
        if (nl & 1) pk[nl >> 1] = (unsigned)prevb | ((unsigned)b << 16);
        else        prevb = b;
    }
    {
        const int nb2 = nb >> 1;               // 0,8,16,24
        uint4 v0 = { pk[0], pk[1], pk[2], pk[3] };
        uint4 v1 = { pk[4], pk[5], pk[6], pk[7] };
        *(uint4*)&Ebu[kql][nb2]     = v0;
        *(uint4*)&Ebu[kql][nb2 + 4] = v1;
    }
    red[tid] = csum;
    __syncthreads();
    if (tid < 64) {
        float v = red[tid] + red[tid + 64] + red[tid + 128] + red[tid + 192];
        part[(size_t)(kq0 + tid) * NB + blockIdx.y] = v;   // plain store
    }

    // ET[kq0+r][n0 + s*16 .. +16): 4 threads cover one 128B row, b128 LDS reads
    const int r = tid >> 2;
    const int s4 = (tid & 3) * 8;
    uint4 w0 = *(const uint4*)&Ebu[r][s4];
    uint4 w1 = *(const uint4*)&Ebu[r][s4 + 4];
    uint4* dst = (uint4*)&ET[(size_t)(kq0 + r) * N + n0 + (tid & 3) * 16];
    dst[0] = w0;
    dst[1] = w1;
}

// ---------------------------------------------------------------------------
// Symmetric GEMM: only upper tiles (ti<=tj), 36 tiles x 16 z-chunks = 576
// blocks. zc = bid&15 -> XCD = bid%8 = zc%8: chunk's 1MB ET slice L2-resident,
// 72 blocks/XCD = 2.25/CU. 128x128 tile, BK=64, dbuf LDS, XOR swizzle.
// Slab layout Gpart[u][z][128][128], coalesced plain stores.
// ---------------------------------------------------------------------------
__global__ __launch_bounds__(256) void k_gemm(
    const unsigned short* __restrict__ ET, float* __restrict__ Gpart,
    int N, int NT)
{
    __shared__ unsigned short At[2][128 * 64];
    __shared__ unsigned short Bt[2][128 * 64];

    const int tid  = threadIdx.x;
    const int wave = tid >> 6, lane = tid & 63;
    const int wi = wave >> 1, wj = wave & 1;

    const int bid = blockIdx.x;
    const int zc  = bid & 15;           // z-chunk (XCD affinity: XCD = zc%8)
    const int uu  = bid >> 4;           // upper-tile index 0..35
    int ti = 0, rem = uu;
    while (rem >= NT - ti) { rem -= NT - ti; ++ti; }
    const int tj = ti + rem;
    const int i0 = ti * 128, j0 = tj * 128;

    const int NS = N >> 4;              // 512 per chunk
    const int nbase = zc * NS;
    const int nsteps = NS >> 6;         // 8

    const int srow = tid >> 3;
    const int sch  = (tid & 7) ^ (srow & 7);
    const size_t gA = (size_t)(i0 + srow) * N + nbase + sch * 8;
    const size_t gB = (size_t)(j0 + srow) * N + nbase + sch * 8;

    f32x16 acc[2][2] = {};

    auto STAGE = [&](int buf, int noff) {
        unsigned short* la = &At[buf][wave * 512];
        unsigned short* lb = &Bt[buf][wave * 512];
#pragma unroll
        for (int b = 0; b < 4; ++b) {
            gload_lds16(ET + gA + (size_t)(b * 32) * N + noff, la + b * 2048);
            gload_lds16(ET + gB + (size_t)(b * 32) * N + noff, lb + b * 2048);
        }
    };

    STAGE(0, 0);
    asm volatile("s_waitcnt vmcnt(0)" ::: "memory");
    __syncthreads();

    for (int t = 0; t < nsteps; ++t) {
        const int buf = t & 1;
        if (t + 1 < nsteps) STAGE(buf ^ 1, (t + 1) * 64);

        const unsigned short* Ab = &At[buf][0];
        const unsigned short* Bb = &Bt[buf][0];
        bf16x8 a[2][4], b[2][4];
#pragma unroll
        for (int m = 0; m < 2; ++m) {
            const int rr = wi * 64 + m * 32 + (lane & 31);
#pragma unroll
            for (int ks = 0; ks < 4; ++ks) {
                const int ch = (ks * 2 + (lane >> 5)) ^ (rr & 7);
                a[m][ks] = *(const bf16x8*)&Ab[rr * 64 + ch * 8];
            }
        }
#pragma unroll
        for (int n = 0; n < 2; ++n) {
            const int rr = wj * 64 + n * 32 + (lane & 31);
#pragma unroll
            for (int ks = 0; ks < 4; ++ks) {
                const int ch = (ks * 2 + (lane >> 5)) ^ (rr & 7);
                b[n][ks] = *(const bf16x8*)&Bb[rr * 64 + ch * 8];
            }
        }
#pragma unroll
        for (int ks = 0; ks < 4; ++ks)
#pragma unroll
            for (int m = 0; m < 2; ++m)
#pragma unroll
                for (int n = 0; n < 2; ++n)
                    acc[m][n] = __builtin_amdgcn_mfma_f32_32x32x16_bf16(
                        a[m][ks], b[n][ks], acc[m][n], 0, 0, 0);

        asm volatile("s_waitcnt vmcnt(0)" ::: "memory");
        __syncthreads();
    }

    // C/D layout (32x32): col = lane&31, row = (reg&3) + 8*(reg>>2) + 4*(lane>>5)
    float* Gp = Gpart + ((size_t)uu * 16 + zc) * 16384;
    const int colb = wj * 64 + (lane & 31);
    const int rowb = wi * 64 + 4 * (lane >> 5);
#pragma unroll
    for (int m = 0; m < 2; ++m)
#pragma unroll
        for (int n = 0; n < 2; ++n)
#pragma unroll
            for (int reg = 0; reg < 16; ++reg) {
                const int row = rowb + m * 32 + (reg & 3) + 8 * (reg >> 2);
                Gp[row * 128 + colb + n * 32] = acc[m][n][reg];
            }
}

// ---------------------------------------------------------------------------
// Reduce: 36 tiles x 4 row-chunks. Sum 16 z-slabs of a 32x128 chunk, write
// it (with diag fix), and mirror-write the transpose via LDS to (tj,ti).
// ---------------------------------------------------------------------------
__global__ __launch_bounds__(256) void k_reduce(
    const float* __restrict__ Gpart, const float* __restrict__ part,
    float* __restrict__ G, int KQ, int NB, int NT)
{
    const int uu = blockIdx.x >> 2;
    const int ch = blockIdx.x & 3;
    int ti = 0, rem = uu;
    while (rem >= NT - ti) { rem -= NT - ti; ++ti; }
    const int tj = ti + rem;

    __shared__ float T[32][132];   // 132: 16B-aligned rows, b128-store clean

    const int tid = threadIdx.x;
    const size_t ub = (size_t)uu * 16 * 16384 + (size_t)ch * 4096;

#pragma unroll
    for (int i = 0; i < 4; ++i) {
        const int lf  = tid + i * 256;
        const int off = lf * 4;
        floatx4 v = *(const floatx4*)&Gpart[ub + off];
#pragma unroll
        for (int z = 1; z < 16; ++z)
            v += *(const floatx4*)&Gpart[ub + (size_t)z * 16384 + off];

        const int rl = lf >> 5;            // 0..31
        const int cl = off & 127;
        const int gi = ti * 128 + ch * 32 + rl;
        const int gj = tj * 128 + cl;
        if (ti == tj && gi >= gj && gi < gj + 4) {
            const floatx4* p = (const floatx4*)&part[(size_t)gi * NB];
            floatx4 a4 = p[0];
            for (int k = 1; k < (NB >> 2); ++k) a4 += p[k];
            v[gi - gj] = a4[0] + a4[1] + a4[2] + a4[3];
        }
        *(floatx4*)&G[(size_t)gi * KQ + gj] = v;
        if (ti != tj) *(floatx4*)&T[rl][cl] = v;
    }

    if (ti == tj) return;
    __syncthreads();

    // mirror: 128 x 32 at rows tj*128.., cols ti*128+ch*32..
#pragma unroll
    for (int i = 0; i < 4; ++i) {
        const int lf2 = tid + i * 256;
        const int r2 = lf2 >> 3;           // 0..127
        const int c2 = (lf2 * 4) & 31;     // 0,4,...,28
        floatx4 v;
        v[0] = T[c2 + 0][r2];
        v[1] = T[c2 + 1][r2];
        v[2] = T[c2 + 2][r2];
        v[3] = T[c2 + 3][r2];
        const int gi = tj * 128 + r2;
        const int gj = ti * 128 + ch * 32 + c2;
        *(floatx4*)&G[(size_t)gi * KQ + gj] = v;
    }
}

// ---------------------------------------------------------------------------
extern "C" void kernel_launch(void* const* d_in, const int* in_sizes, int n_in,
                              void* d_out, int out_size, void* d_ws, size_t ws_size,
                              hipStream_t stream)
{
    (void)n_in; (void)out_size; (void)ws_size;
    const float* X      = (const float*)d_in[0];
    const float* z      = (const float*)d_in[1];
    const float* weight = (const float*)d_in[2];
    const float* mu     = (const float*)d_in[3];
    const float* stdv   = (const float*)d_in[4];
    const float* alpha  = (const float*)d_in[5];
    const float* vmw    = (const float*)d_in[6];
    const float* vsw    = (const float*)d_in[7];

    const int N  = in_sizes[0] / 8;   // 8192
    const int KQ = in_sizes[5];       // 1024
    const int NB = N / 64;            // 128
    const int NT = KQ >> 7;           // 8 tile-rows
    const int NU = NT * (NT + 1) / 2; // 36 upper tiles

    size_t o = 0;
    unsigned short* ET = (unsigned short*)d_ws;          o += (size_t)KQ * N * 2;   // 16 MB
    float* Gpart = (float*)((char*)d_ws + o);            o += (size_t)NU * 16 * 16384 * 4; // 36.9 MB
    float* part  = (float*)((char*)d_ws + o);            o += (size_t)KQ * NB * 4;  // 512 KB
    float* coef  = (float*)((char*)d_ws + o);

    float* Ephi = (float*)d_out;
    float* G    = Ephi + (size_t)N * KQ;
    float* Ecos = G + (size_t)KQ * KQ;

    k_precompute<<<4, 256, 0, stream>>>(z, weight, mu, stdv, alpha, vmw, vsw, coef);
    k_ephi<<<dim3(KQ / 64, NB), 256, 0, stream>>>(
        X, coef, Ephi, Ecos, ET, part, N, NB);
    k_gemm<<<NU * 16, 256, 0, stream>>>(ET, Gpart, N, NT);
    k_reduce<<<NU * 4, 256, 0, stream>>>(Gpart, part, G, KQ, NB, NT);
}

// Round 8
// 143.160 us; speedup vs baseline: 1.1086x; 1.1086x over previous
//
#include <hip/hip_runtime.h>

#define TWO_PI 6.2831853071795864769f

typedef float floatx4 __attribute__((ext_vector_type(4)));
typedef float f32x16 __attribute__((ext_vector_type(16)));
typedef __bf16 bf16x8 __attribute__((ext_vector_type(8)));

__device__ __forceinline__ unsigned short f32_to_bf16(float f) {
    unsigned int u = __float_as_uint(f);
    u += 0x7fffu + ((u >> 16) & 1u);   // round-to-nearest-even
    return (unsigned short)(u >> 16);
}

__device__ __forceinline__ void gload_lds16(const void* g, void* l) {
    __builtin_amdgcn_global_load_lds(
        (__attribute__((address_space(1))) unsigned int*)g,
        (__attribute__((address_space(3))) unsigned int*)l, 16, 0, 0);
}

// ---------------------------------------------------------------------------
// Precompute per-(d,kq) coefficients (separate tiny kernel — L2-speed).
// coef row (32 floats): Ac[0..7]=2pi*E_w, u[0..7]=(2pi*std_p)^2*vsw, z[0..7],
//                       alpha, sqrt(2w/K), 2w/K
// ---------------------------------------------------------------------------
__global__ __launch_bounds__(256) void k_precompute(
    const float* __restrict__ z, const float* __restrict__ weight,
    const float* __restrict__ mu, const float* __restrict__ stdv,
    const float* __restrict__ alpha, const float* __restrict__ vmw,
    const float* __restrict__ vsw, float* __restrict__ coef)
{
    int kq = blockIdx.x * blockDim.x + threadIdx.x;
    if (kq >= 1024) return;
    int q = kq & 15;
    float w = weight[q];
    float t2k = w * (2.0f / 64.0f);
    float* c = coef + (size_t)kq * 32;
#pragma unroll
    for (int d = 0; d < 8; ++d) {
        float m = mu[d * 16 + q];
        float s = stdv[d * 16 + q];
        float mean_p = 1.0f / (m + 1e-8f);
        float std_p  = 1.0f / (TWO_PI * s + 1e-8f);
        float Ew  = mean_p + std_p * vmw[d * 1024 + kq];
        float sp2 = std_p * TWO_PI;
        c[d]      = TWO_PI * Ew;
        c[8 + d]  = sp2 * sp2 * vsw[d * 1024 + kq];
        c[16 + d] = z[d * 1024 + kq];
    }
    c[24] = alpha[kq];
    c[25] = sqrtf(t2k);
    c[26] = t2k;
}

// ---------------------------------------------------------------------------
// Elementwise kernel: 64 n-rows x 64 kq-cols per block, 256 threads.
// (byte-identical to round 7 — isolation control)
// ---------------------------------------------------------------------------
__global__ __launch_bounds__(256) void k_ephi(
    const float* __restrict__ X, const float* __restrict__ coef,
    float* __restrict__ Ephi, float* __restrict__ Ecos,
    unsigned short* __restrict__ ET, float* __restrict__ part,
    int N, int NB)
{
    __shared__ float Xs[64][8];
    __shared__ unsigned Ebu[64][36];   // [kq_local][n_pair]; pad 36 -> b128 ok
    __shared__ float red[256];

    const int tid = threadIdx.x;
    const int kq0 = blockIdx.x * 64;
    const int n0  = blockIdx.y * 64;

    for (int i = tid; i < 512; i += 256)
        Xs[i >> 3][i & 7] = X[(size_t)(n0 + (i >> 3)) * 8 + (i & 7)];
    __syncthreads();

    const int kql = tid & 63;
    const int kq  = kq0 + kql;
    const int nb  = (tid >> 6) * 16;

    const float* c = coef + (size_t)kq * 32;
    float Ac[8], u[8], zv[8];
    *(floatx4*)&Ac[0] = *(const floatx4*)(c + 0);
    *(floatx4*)&Ac[4] = *(const floatx4*)(c + 4);
    *(floatx4*)&u[0]  = *(const floatx4*)(c + 8);
    *(floatx4*)&u[4]  = *(const floatx4*)(c + 12);
    *(floatx4*)&zv[0] = *(const floatx4*)(c + 16);
    *(floatx4*)&zv[4] = *(const floatx4*)(c + 20);
    const float alp = c[24], sqw = c[25], t2k = c[26];

    float csum = 0.0f;
    unsigned pk[8];
    unsigned short prevb = 0;
#pragma unroll
    for (int nl = 0; nl < 16; ++nl) {
        const int n = nb + nl;
        floatx4 xa = *(const floatx4*)&Xs[n][0];
        floatx4 xb = *(const floatx4*)&Xs[n][4];
        float ph = 0.0f, s = 0.0f;
#pragma unroll
        for (int d = 0; d < 4; ++d) {
            float t = xa[d] - zv[d];
            ph = fmaf(Ac[d], t, ph);
            s  = fmaf(u[d], t * t, s);
        }
#pragma unroll
        for (int d = 0; d < 4; ++d) {
            float t = xb[d] - zv[4 + d];
            ph = fmaf(Ac[4 + d], t, ph);
            s  = fmaf(u[4 + d], t * t, s);
        }
        float cw  = __cosf(alp + ph);           // |arg| <~ few hundred: err ~1e-5
        float dec = __expf(-0.5f * s);
        float ep  = sqw * dec * cw;
        float d2  = dec * dec;
        float c2w = fmaf(2.0f * cw, cw, -1.0f); // cos(2(alpha+phase))
        float ec  = t2k * fmaf(0.5f * d2 * d2, c2w, 0.5f);
        csum += ec;
        size_t idx = (size_t)(n0 + n) * 1024 + kq;
        __builtin_nontemporal_store(ep, &Ephi[idx]);
        __builtin_nontemporal_store(ec, &Ecos[idx]);
        unsigned short b = f32_to_bf16(ep);
        if (nl & 1) pk[nl >> 1] = (unsigned)prevb | ((unsigned)b << 16);
        else        prevb = b;
    }
    {
        const int nb2 = nb >> 1;               // 0,8,16,24
        uint4 v0 = { pk[0], pk[1], pk[2], pk[3] };
        uint4 v1 = { pk[4], pk[5], pk[6], pk[7] };
        *(uint4*)&Ebu[kql][nb2]     = v0;
        *(uint4*)&Ebu[kql][nb2 + 4] = v1;
    }
    red[tid] = csum;
    __syncthreads();
    if (tid < 64) {
        float v = red[tid] + red[tid + 64] + red[tid + 128] + red[tid + 192];
        part[(size_t)(kq0 + tid) * NB + blockIdx.y] = v;   // plain store
    }

    // ET[kq0+r][n0 + s*16 .. +16): 4 threads cover one 128B row, b128 LDS reads
    const int r = tid >> 2;
    const int s4 = (tid & 3) * 8;
    uint4 w0 = *(const uint4*)&Ebu[r][s4];
    uint4 w1 = *(const uint4*)&Ebu[r][s4 + 4];
    uint4* dst = (uint4*)&ET[(size_t)(kq0 + r) * N + n0 + (tid & 3) * 16];
    dst[0] = w0;
    dst[1] = w1;
}

// ---------------------------------------------------------------------------
// Symmetric GEMM: 36 upper tiles (ti<=tj) x 14 K-chunks = 504 blocks <= 512
// residency slots (2/CU at 64KB LDS) -> all blocks start at t0, uniform
// 9-10 steps each (chunks 0,1 take 10x64, chunks 2..13 take 9x64).
// 128x128 tile, BK=64, dbuf LDS, XOR swizzle. NT slab stores.
// ---------------------------------------------------------------------------
__global__ __launch_bounds__(256) void k_gemm(
    const unsigned short* __restrict__ ET, float* __restrict__ Gpart,
    int N, int NT)
{
    __shared__ unsigned short At[2][128 * 64];
    __shared__ unsigned short Bt[2][128 * 64];

    const int tid  = threadIdx.x;
    const int wave = tid >> 6, lane = tid & 63;
    const int wi = wave >> 1, wj = wave & 1;

    const int bid = blockIdx.x;
    const int uu  = bid / 14;           // upper-tile index 0..35
    const int zc  = bid - uu * 14;      // K-chunk 0..13
    int ti = 0, rem = uu;
    while (rem >= NT - ti) { rem -= NT - ti; ++ti; }
    const int tj = ti + rem;
    const int i0 = ti * 128, j0 = tj * 128;

    const int nsteps = 9 + (zc < 2 ? 1 : 0);
    const int nbase  = (zc * 9 + (zc < 2 ? zc : 2)) * 64;

    const int srow = tid >> 3;
    const int sch  = (tid & 7) ^ (srow & 7);
    const size_t gA = (size_t)(i0 + srow) * N + nbase + sch * 8;
    const size_t gB = (size_t)(j0 + srow) * N + nbase + sch * 8;

    f32x16 acc[2][2] = {};

    auto STAGE = [&](int buf, int noff) {
        unsigned short* la = &At[buf][wave * 512];
        unsigned short* lb = &Bt[buf][wave * 512];
#pragma unroll
        for (int b = 0; b < 4; ++b) {
            gload_lds16(ET + gA + (size_t)(b * 32) * N + noff, la + b * 2048);
            gload_lds16(ET + gB + (size_t)(b * 32) * N + noff, lb + b * 2048);
        }
    };

    STAGE(0, 0);
    asm volatile("s_waitcnt vmcnt(0)" ::: "memory");
    __syncthreads();

    for (int t = 0; t < nsteps; ++t) {
        const int buf = t & 1;
        if (t + 1 < nsteps) STAGE(buf ^ 1, (t + 1) * 64);

        const unsigned short* Ab = &At[buf][0];
        const unsigned short* Bb = &Bt[buf][0];
        bf16x8 a[2][4], b[2][4];
#pragma unroll
        for (int m = 0; m < 2; ++m) {
            const int rr = wi * 64 + m * 32 + (lane & 31);
#pragma unroll
            for (int ks = 0; ks < 4; ++ks) {
                const int ch = (ks * 2 + (lane >> 5)) ^ (rr & 7);
                a[m][ks] = *(const bf16x8*)&Ab[rr * 64 + ch * 8];
            }
        }
#pragma unroll
        for (int n = 0; n < 2; ++n) {
            const int rr = wj * 64 + n * 32 + (lane & 31);
#pragma unroll
            for (int ks = 0; ks < 4; ++ks) {
                const int ch = (ks * 2 + (lane >> 5)) ^ (rr & 7);
                b[n][ks] = *(const bf16x8*)&Bb[rr * 64 + ch * 8];
            }
        }
#pragma unroll
        for (int ks = 0; ks < 4; ++ks)
#pragma unroll
            for (int m = 0; m < 2; ++m)
#pragma unroll
                for (int n = 0; n < 2; ++n)
                    acc[m][n] = __builtin_amdgcn_mfma_f32_32x32x16_bf16(
                        a[m][ks], b[n][ks], acc[m][n], 0, 0, 0);

        asm volatile("s_waitcnt vmcnt(0)" ::: "memory");
        __syncthreads();
    }

    // C/D layout (32x32): col = lane&31, row = (reg&3) + 8*(reg>>2) + 4*(lane>>5)
    float* Gp = Gpart + (size_t)bid * 16384;
    const int colb = wj * 64 + (lane & 31);
    const int rowb = wi * 64 + 4 * (lane >> 5);
#pragma unroll
    for (int m = 0; m < 2; ++m)
#pragma unroll
        for (int n = 0; n < 2; ++n)
#pragma unroll
            for (int reg = 0; reg < 16; ++reg) {
                const int row = rowb + m * 32 + (reg & 3) + 8 * (reg >> 2);
                __builtin_nontemporal_store(
                    acc[m][n][reg], &Gp[row * 128 + colb + n * 32]);
            }
}

// ---------------------------------------------------------------------------
// Reduce: 36 tiles x 8 row-chunks (16 rows each) = 288 blocks. Sum 14
// z-slabs, write chunk (with diag fix), mirror-write transpose via LDS.
// ---------------------------------------------------------------------------
__global__ __launch_bounds__(256) void k_reduce(
    const float* __restrict__ Gpart, const float* __restrict__ part,
    float* __restrict__ G, int KQ, int NB, int NT)
{
    const int uu = blockIdx.x >> 3;
    const int ch = blockIdx.x & 7;
    int ti = 0, rem = uu;
    while (rem >= NT - ti) { rem -= NT - ti; ++ti; }
    const int tj = ti + rem;

    __shared__ float T[16][132];

    const int tid = threadIdx.x;
    const size_t ub = (size_t)uu * 14 * 16384 + (size_t)ch * 2048;

#pragma unroll
    for (int i = 0; i < 2; ++i) {
        const int lf  = tid + i * 256;
        const int off = lf * 4;
        floatx4 v = *(const floatx4*)&Gpart[ub + off];
#pragma unroll
        for (int z = 1; z < 14; ++z)
            v += *(const floatx4*)&Gpart[ub + (size_t)z * 16384 + off];

        const int rl = lf >> 5;            // 0..15
        const int cl = off & 127;
        const int gi = ti * 128 + ch * 16 + rl;
        const int gj = tj * 128 + cl;
        if (ti == tj && gi >= gj && gi < gj + 4) {
            const floatx4* p = (const floatx4*)&part[(size_t)gi * NB];
            floatx4 a4 = p[0];
            for (int k = 1; k < (NB >> 2); ++k) a4 += p[k];
            v[gi - gj] = a4[0] + a4[1] + a4[2] + a4[3];
        }
        *(floatx4*)&G[(size_t)gi * KQ + gj] = v;
        if (ti != tj) *(floatx4*)&T[rl][cl] = v;
    }

    if (ti == tj) return;
    __syncthreads();

    // mirror: 128 x 16 at rows tj*128.., cols ti*128+ch*16..
#pragma unroll
    for (int i = 0; i < 2; ++i) {
        const int lf2 = tid + i * 256;
        const int r2 = lf2 >> 2;           // 0..127
        const int c2 = (lf2 & 3) * 4;      // 0,4,8,12
        floatx4 v;
        v[0] = T[c2 + 0][r2];
        v[1] = T[c2 + 1][r2];
        v[2] = T[c2 + 2][r2];
        v[3] = T[c2 + 3][r2];
        const int gi = tj * 128 + r2;
        const int gj = ti * 128 + ch * 16 + c2;
        *(floatx4*)&G[(size_t)gi * KQ + gj] = v;
    }
}

// ---------------------------------------------------------------------------
extern "C" void kernel_launch(void* const* d_in, const int* in_sizes, int n_in,
                              void* d_out, int out_size, void* d_ws, size_t ws_size,
                              hipStream_t stream)
{
    (void)n_in; (void)out_size; (void)ws_size;
    const float* X      = (const float*)d_in[0];
    const float* z      = (const float*)d_in[1];
    const float* weight = (const float*)d_in[2];
    const float* mu     = (const float*)d_in[3];
    const float* stdv   = (const float*)d_in[4];
    const float* alpha  = (const float*)d_in[5];
    const float* vmw    = (const float*)d_in[6];
    const float* vsw    = (const float*)d_in[7];

    const int N  = in_sizes[0] / 8;   // 8192
    const int KQ = in_sizes[5];       // 1024
    const int NB = N / 64;            // 128
    const int NT = KQ >> 7;           // 8 tile-rows
    const int NU = NT * (NT + 1) / 2; // 36 upper tiles
    const int NZ = 14;                // K-chunks -> 504 blocks

    size_t o = 0;
    unsigned short* ET = (unsigned short*)d_ws;          o += (size_t)KQ * N * 2;   // 16 MB
    float* Gpart = (float*)((char*)d_ws + o);            o += (size_t)NU * NZ * 16384 * 4; // 33 MB
    float* part  = (float*)((char*)d_ws + o);            o += (size_t)KQ * NB * 4;  // 512 KB
    float* coef  = (float*)((char*)d_ws + o);

    float* Ephi = (float*)d_out;
    float* G    = Ephi + (size_t)N * KQ;
    float* Ecos = G + (size_t)KQ * KQ;

    k_precompute<<<4, 256, 0, stream>>>(z, weight, mu, stdv, alpha, vmw, vsw, coef);
    k_ephi<<<dim3(KQ / 64, NB), 256, 0, stream>>>(
        X, coef, Ephi, Ecos, ET, part, N, NB);
    k_gemm<<<NU * NZ, 256, 0, stream>>>(ET, Gpart, N, NT);
    k_reduce<<<NU * 8, 256, 0, stream>>>(Gpart, part, G, KQ, NB, NT);
}